// Round 1
// baseline (2934.228 us; speedup 1.0000x reference)
//
#include <hip/hip_runtime.h>
#include <math.h>

// ---- problem constants ----
#define BQ 2
#define LQ 4096
#define MTOK (BQ*LQ)        // 8192 tokens
#define HID 2048
#define NHEADS 16
#define DHEAD 64
#define ENG 1024
#define VOCAB 129280
#define HC 4
#define KSZ 4
#define DIL 3
#define EPS_RMS 1.1920929e-07f
#define EPS_SC  1e-05f
#define INV_SQRT_HID 0.022097086912079608f  // 1/sqrt(2048)

// ---- tile config for fp32 GEMM ----
#define BM 64
#define BN 64
#define BK 16

// ============================================================
// 1) gather: emb[t][k] = emb_tables[h=k/64][hash_ids[t][h]][k%64]
// ============================================================
__global__ __launch_bounds__(256) void gather_kernel(
        const int* __restrict__ hash_ids,
        const float* __restrict__ emb_tables,
        float* __restrict__ emb)
{
    int t = blockIdx.x;
    int tid = threadIdx.x;
    const int* ids = hash_ids + (size_t)t * NHEADS;
    #pragma unroll
    for (int i = 0; i < 4; ++i) {
        int k = tid + i * 256;
        int h = k >> 6;
        int d = k & 63;
        int id = ids[h];
        emb[(size_t)t * ENG + k] = emb_tables[((size_t)h * VOCAB + (size_t)id) * DHEAD + d];
    }
}

// ============================================================
// 2) value GEMM: vraw = emb @ value_w + value_b   [MTOK x HID]
// ============================================================
__global__ __launch_bounds__(256) void gemm_value_kernel(
        const float* __restrict__ A,    // emb [MTOK][ENG]
        const float* __restrict__ Bw,   // value_w [ENG][HID]
        const float* __restrict__ bias, // value_b [HID]
        float* __restrict__ C)          // vraw [MTOK][HID]
{
    __shared__ float As[BK][BM + 4];
    __shared__ float Bs[BK][BN];
    int tid = threadIdx.x;
    int tx = tid & 15, ty = tid >> 4;
    int m0 = blockIdx.y * BM;
    int n0 = blockIdx.x * BN;
    float acc[4][4] = {};
    for (int k0 = 0; k0 < ENG; k0 += BK) {
        #pragma unroll
        for (int i = 0; i < 4; ++i) {
            int e = tid + i * 256;
            int ar = e >> 4, ac = e & 15;
            As[ac][ar] = A[(size_t)(m0 + ar) * ENG + k0 + ac];
        }
        #pragma unroll
        for (int i = 0; i < 4; ++i) {
            int e = tid + i * 256;
            int br = e >> 6, bc = e & 63;
            Bs[br][bc] = Bw[(size_t)(k0 + br) * HID + n0 + bc];
        }
        __syncthreads();
        #pragma unroll
        for (int kk = 0; kk < BK; ++kk) {
            float a[4], b[4];
            #pragma unroll
            for (int r = 0; r < 4; ++r) a[r] = As[kk][ty * 4 + r];
            #pragma unroll
            for (int c = 0; c < 4; ++c) b[c] = Bs[kk][tx * 4 + c];
            #pragma unroll
            for (int r = 0; r < 4; ++r)
                #pragma unroll
                for (int c = 0; c < 4; ++c)
                    acc[r][c] += a[r] * b[c];
        }
        __syncthreads();
    }
    #pragma unroll
    for (int r = 0; r < 4; ++r) {
        int m = m0 + ty * 4 + r;
        #pragma unroll
        for (int c = 0; c < 4; ++c) {
            int n = n0 + tx * 4 + c;
            C[(size_t)m * HID + n] = acc[r][c] + bias[n];
        }
    }
}

// ============================================================
// 3) keys GEMM with fused gate-partial epilogue (keys never stored)
//    p_sq[t][g]  += sum_h keys^2
//    p_dot[t][g] += sum_h keys * hid * w1 * w2
// ============================================================
__global__ __launch_bounds__(256) void gemm_keys_kernel(
        const float* __restrict__ A,      // emb
        const float* __restrict__ key_w,  // [HC][ENG][HID]
        const float* __restrict__ key_b,  // [HC][HID]
        const float* __restrict__ hidden, // [MTOK][HID]
        const float* __restrict__ w1,     // norm1_w [HC][HID]
        const float* __restrict__ w2,     // norm2_w [HC][HID]
        float* __restrict__ p_sq,         // [MTOK][HC]
        float* __restrict__ p_dot)        // [MTOK][HC]
{
    __shared__ float As[BK][BM + 4];
    __shared__ float Bs[BK][BN];
    __shared__ float redsq[BM][17];
    __shared__ float reddot[BM][17];
    int tid = threadIdx.x;
    int tx = tid & 15, ty = tid >> 4;
    int m0 = blockIdx.y * BM;
    int n0 = blockIdx.x * BN;          // global col in [0, HC*HID)
    int g = n0 >> 11;                  // channel
    int cbase = n0 & (HID - 1);        // col within channel
    const float* Bw = key_w + (size_t)g * ENG * HID;
    float acc[4][4] = {};
    for (int k0 = 0; k0 < ENG; k0 += BK) {
        #pragma unroll
        for (int i = 0; i < 4; ++i) {
            int e = tid + i * 256;
            int ar = e >> 4, ac = e & 15;
            As[ac][ar] = A[(size_t)(m0 + ar) * ENG + k0 + ac];
        }
        #pragma unroll
        for (int i = 0; i < 4; ++i) {
            int e = tid + i * 256;
            int br = e >> 6, bc = e & 63;
            Bs[br][bc] = Bw[(size_t)(k0 + br) * HID + cbase + bc];
        }
        __syncthreads();
        #pragma unroll
        for (int kk = 0; kk < BK; ++kk) {
            float a[4], b[4];
            #pragma unroll
            for (int r = 0; r < 4; ++r) a[r] = As[kk][ty * 4 + r];
            #pragma unroll
            for (int c = 0; c < 4; ++c) b[c] = Bs[kk][tx * 4 + c];
            #pragma unroll
            for (int r = 0; r < 4; ++r)
                #pragma unroll
                for (int c = 0; c < 4; ++c)
                    acc[r][c] += a[r] * b[c];
        }
        __syncthreads();
    }
    // epilogue: per-row partial reductions of keys^2 and keys*hid*w1*w2
    float psq[4] = {0.f, 0.f, 0.f, 0.f};
    float pdt[4] = {0.f, 0.f, 0.f, 0.f};
    #pragma unroll
    for (int r = 0; r < 4; ++r) {
        int m = m0 + ty * 4 + r;
        #pragma unroll
        for (int c = 0; c < 4; ++c) {
            int n = cbase + tx * 4 + c;
            float v = acc[r][c] + key_b[(size_t)g * HID + n];
            float hv = hidden[(size_t)m * HID + n];
            float w = w1[(size_t)g * HID + n] * w2[(size_t)g * HID + n];
            psq[r] += v * v;
            pdt[r] += v * hv * w;
        }
    }
    #pragma unroll
    for (int r = 0; r < 4; ++r) {
        redsq[ty * 4 + r][tx] = psq[r];
        reddot[ty * 4 + r][tx] = pdt[r];
    }
    __syncthreads();
    if (tid < BM) {
        float ssq = 0.f, sdt = 0.f;
        #pragma unroll
        for (int j = 0; j < 16; ++j) { ssq += redsq[tid][j]; sdt += reddot[tid][j]; }
        int m = m0 + tid;
        atomicAdd(&p_sq[(size_t)m * HC + g], ssq);
        atomicAdd(&p_dot[(size_t)m * HC + g], sdt);
    }
}

// ============================================================
// 4) per-token stats: mq = mean(hid^2), msqv = mean(vraw^2)
// ============================================================
__global__ __launch_bounds__(256) void stats_kernel(
        const float* __restrict__ hidden,
        const float* __restrict__ vraw,
        float* __restrict__ mq,
        float* __restrict__ msqv)
{
    int t = blockIdx.x;
    int tid = threadIdx.x;
    const float4* hp = (const float4*)(hidden + (size_t)t * HID);
    const float4* vp = (const float4*)(vraw + (size_t)t * HID);
    float sh = 0.f, sv = 0.f;
    for (int i = tid; i < HID / 4; i += 256) {
        float4 h4 = hp[i];
        sh += h4.x * h4.x + h4.y * h4.y + h4.z * h4.z + h4.w * h4.w;
        float4 v4 = vp[i];
        sv += v4.x * v4.x + v4.y * v4.y + v4.z * v4.z + v4.w * v4.w;
    }
    __shared__ float s1[256], s2[256];
    s1[tid] = sh; s2[tid] = sv;
    __syncthreads();
    for (int off = 128; off > 0; off >>= 1) {
        if (tid < off) { s1[tid] += s1[tid + off]; s2[tid] += s2[tid + off]; }
        __syncthreads();
    }
    if (tid == 0) { mq[t] = s1[0] / HID; msqv[t] = s2[0] / HID; }
}

// ============================================================
// 5) gate finalize: gate[t][g], c[t][g]
// ============================================================
__global__ __launch_bounds__(256) void finalize_kernel(
        const float* __restrict__ p_sq,
        const float* __restrict__ p_dot,
        const float* __restrict__ mq,
        const float* __restrict__ msqv,
        float* __restrict__ gate,
        float* __restrict__ cc)
{
    int i = blockIdx.x * 256 + threadIdx.x;
    if (i >= MTOK * HC) return;
    int t = i >> 2;
    float mk = p_sq[i] / HID + EPS_RMS;
    float mqv = mq[t] + EPS_RMS;
    float raw = p_dot[i] * rsqrtf(mk) * rsqrtf(mqv) * INV_SQRT_HID;
    float g2 = copysignf(sqrtf(fmaxf(fabsf(raw), 1e-6f)), raw);
    float gt = 1.0f / (1.0f + expf(-g2));
    gate[i] = gt;
    cc[i] = gt * rsqrtf(gt * gt * msqv[t] + EPS_SC);
}

// ============================================================
// 6) fused conv + silu + gated-value + channel sum
//    out[t][h] = vraw[t][h]*sum_g(gate) + sum_g silu(sc_w[g][h] *
//                sum_k conv_w[g*HID+h][k]*c[t+3k-9][g]*vraw[t+3k-9][h])
// ============================================================
__global__ __launch_bounds__(256) void final_kernel(
        const float* __restrict__ vraw,
        const float* __restrict__ gate,
        const float* __restrict__ cc,
        const float* __restrict__ sc_w,   // [HC][HID]
        const float* __restrict__ conv_w, // [HC*HID][K]
        float* __restrict__ out)
{
    int t = blockIdx.x;
    int l = t & (LQ - 1);
    int tid = threadIdx.x;
    float G = gate[t * 4 + 0] + gate[t * 4 + 1] + gate[t * 4 + 2] + gate[t * 4 + 3];
    float cg[4][4];   // [tap k][g]
    int tki[4];
    #pragma unroll
    for (int k = 0; k < 4; ++k) {
        int lk = l + 3 * k - 9;
        bool valid = (lk >= 0);
        int tk = t + 3 * k - 9;
        tki[k] = valid ? tk : -1;
        #pragma unroll
        for (int g = 0; g < 4; ++g)
            cg[k][g] = valid ? cc[tk * 4 + g] : 0.0f;
    }
    #pragma unroll
    for (int i = 0; i < 2; ++i) {
        int h4 = tid + i * 256;   // float4 index in row
        float4 vk[4];
        #pragma unroll
        for (int k = 0; k < 4; ++k) {
            vk[k] = (tki[k] >= 0)
                  ? ((const float4*)(vraw + (size_t)tki[k] * HID))[h4]
                  : make_float4(0.f, 0.f, 0.f, 0.f);
        }
        float res[4];
        #pragma unroll
        for (int j = 0; j < 4; ++j) {
            int h = h4 * 4 + j;
            float vt = ((const float*)&vk[3])[j];   // tap k=3 is t itself
            float o = vt * G;
            #pragma unroll
            for (int g = 0; g < 4; ++g) {
                float4 w4 = ((const float4*)conv_w)[(size_t)g * HID + h];
                float y = w4.x * cg[0][g] * ((const float*)&vk[0])[j]
                        + w4.y * cg[1][g] * ((const float*)&vk[1])[j]
                        + w4.z * cg[2][g] * ((const float*)&vk[2])[j]
                        + w4.w * cg[3][g] * ((const float*)&vk[3])[j];
                y *= sc_w[(size_t)g * HID + h];
                o += y / (1.0f + expf(-y));   // silu
            }
            res[j] = o;
        }
        ((float4*)(out + (size_t)t * HID))[h4] = make_float4(res[0], res[1], res[2], res[3]);
    }
}

// ============================================================
extern "C" void kernel_launch(void* const* d_in, const int* in_sizes, int n_in,
                              void* d_out, int out_size, void* d_ws, size_t ws_size,
                              hipStream_t stream)
{
    const float* hidden     = (const float*)d_in[0];
    const int*   hash_ids   = (const int*)  d_in[1];
    const float* emb_tables = (const float*)d_in[2];
    const float* value_w    = (const float*)d_in[3];
    const float* value_b    = (const float*)d_in[4];
    const float* key_w      = (const float*)d_in[5];
    const float* key_b      = (const float*)d_in[6];
    const float* norm1_w    = (const float*)d_in[7];
    const float* norm2_w    = (const float*)d_in[8];
    const float* sc_norm_w  = (const float*)d_in[9];
    const float* conv_w     = (const float*)d_in[10];
    float* out = (float*)d_out;

    char* ws = (char*)d_ws;
    float* ws_emb  = (float*)ws;  ws += sizeof(float) * (size_t)MTOK * ENG;   // 32 MB
    float* ws_vraw = (float*)ws;  ws += sizeof(float) * (size_t)MTOK * HID;   // 64 MB
    float* ws_psq  = (float*)ws;  ws += sizeof(float) * (size_t)MTOK * HC;
    float* ws_pdot = (float*)ws;  ws += sizeof(float) * (size_t)MTOK * HC;
    float* ws_mq   = (float*)ws;  ws += sizeof(float) * (size_t)MTOK;
    float* ws_msqv = (float*)ws;  ws += sizeof(float) * (size_t)MTOK;
    float* ws_gate = (float*)ws;  ws += sizeof(float) * (size_t)MTOK * HC;
    float* ws_cc   = (float*)ws;  ws += sizeof(float) * (size_t)MTOK * HC;

    // zero the atomic accumulators (psq+pdot are adjacent)
    hipMemsetAsync(ws_psq, 0, sizeof(float) * (size_t)MTOK * HC * 2, stream);

    gather_kernel<<<MTOK, 256, 0, stream>>>(hash_ids, emb_tables, ws_emb);

    gemm_value_kernel<<<dim3(HID / BN, MTOK / BM), 256, 0, stream>>>(
        ws_emb, value_w, value_b, ws_vraw);

    gemm_keys_kernel<<<dim3(HC * HID / BN, MTOK / BM), 256, 0, stream>>>(
        ws_emb, key_w, key_b, hidden, norm1_w, norm2_w, ws_psq, ws_pdot);

    stats_kernel<<<MTOK, 256, 0, stream>>>(hidden, ws_vraw, ws_mq, ws_msqv);

    finalize_kernel<<<(MTOK * HC + 255) / 256, 256, 0, stream>>>(
        ws_psq, ws_pdot, ws_mq, ws_msqv, ws_gate, ws_cc);

    final_kernel<<<MTOK, 256, 0, stream>>>(
        ws_vraw, ws_gate, ws_cc, sc_norm_w, conv_w, out);
}

// Round 2
// 1182.945 us; speedup vs baseline: 2.4804x; 2.4804x over previous
//
#include <hip/hip_runtime.h>
#include <math.h>

// ---- problem constants ----
#define LQ 4096
#define MTOK 8192
#define HID 2048
#define NHEADS 16
#define DHEAD 64
#define ENG 1024
#define VOCAB 129280
#define HC 4
#define EPS_RMS 1.1920929e-07f
#define EPS_SC  1e-05f
#define INV_SQRT_HID 0.022097086912079608f  // 1/sqrt(2048)

typedef __bf16 bf16;
typedef __attribute__((ext_vector_type(8))) __bf16 bf16x8;
typedef __attribute__((ext_vector_type(4))) __bf16 bf16x4;
typedef __attribute__((ext_vector_type(4))) float f32x4;

#define AS1 __attribute__((address_space(1)))
#define AS3 __attribute__((address_space(3)))

__device__ __forceinline__ void gl_lds16(const void* g, void* l) {
    __builtin_amdgcn_global_load_lds((const AS1 unsigned int*)g,
                                     (AS3 unsigned int*)l, 16, 0, 0);
}

// ============================================================
// 1) gather -> bf16 emb [MTOK][ENG]
// ============================================================
__global__ __launch_bounds__(256) void gather_kernel(
        const int* __restrict__ hash_ids,
        const float* __restrict__ emb_tables,
        bf16* __restrict__ emb)
{
    int t = blockIdx.x;
    int tid = threadIdx.x;
    const int* ids = hash_ids + (size_t)t * NHEADS;
    int k = tid * 4;
    int h = k >> 6, d = k & 63;
    int id = ids[h];
    float4 v = *(const float4*)(emb_tables + ((size_t)h * VOCAB + (size_t)id) * DHEAD + d);
    bf16x4 o = {(bf16)v.x, (bf16)v.y, (bf16)v.z, (bf16)v.w};
    *(bf16x4*)(emb + (size_t)t * ENG + k) = o;
}

// ============================================================
// 2) transpose+convert weights: [ENG][HID] fp32 -> [HID][ENG] bf16
//    z==0: value_w, z=1..4: key_w channel z-1
// ============================================================
__global__ __launch_bounds__(256) void transpose_kernel(
        const float* __restrict__ value_w,
        const float* __restrict__ key_w,
        bf16* __restrict__ vwT,
        bf16* __restrict__ kwT)
{
    __shared__ float tile[32][33];
    int z = blockIdx.z;
    const float* src = (z == 0) ? value_w : key_w + (size_t)(z - 1) * ENG * HID;
    bf16* dst = (z == 0) ? vwT : kwT + (size_t)(z - 1) * HID * ENG;
    int c0 = blockIdx.x * 32, r0 = blockIdx.y * 32;
    int tx = threadIdx.x & 31, ty = threadIdx.x >> 5;   // ty: 0..7
    #pragma unroll
    for (int i = 0; i < 4; ++i)
        tile[ty + i * 8][tx] = src[(size_t)(r0 + ty + i * 8) * HID + c0 + tx];
    __syncthreads();
    #pragma unroll
    for (int i = 0; i < 4; ++i)
        dst[(size_t)(c0 + ty + i * 8) * ENG + r0 + tx] = (bf16)tile[tx][ty + i * 8];
}

// ============================================================
// 3) value MFMA GEMM: vraw = emb @ value_w + b, fused sum(vraw^2)
//    A [M][K] bf16 row-major, Bt [N][K] bf16 row-major
// ============================================================
__global__ __launch_bounds__(256, 1) void gemm_value_mfma(
        const bf16* __restrict__ A,
        const bf16* __restrict__ Bt,
        const float* __restrict__ bias,
        float* __restrict__ C,
        float* __restrict__ pv2)
{
    __shared__ __align__(16) bf16 sA[128 * 64];
    __shared__ __align__(16) bf16 sB[128 * 64];
    int tid = threadIdx.x;
    int L = tid & 63, w = tid >> 6;
    int m0 = blockIdx.y * 128, n0 = blockIdx.x * 128;
    int mw = (w & 1) * 64, nw = (w >> 1) * 64;
    int lrow = L >> 3;
    int kcS = ((L & 7) ^ lrow) * 8;     // XOR-swizzled k elem offset for staging
    int lane15 = L & 15, quad = L >> 4;

    f32x4 acc[4][4];
    #pragma unroll
    for (int fm = 0; fm < 4; ++fm)
        #pragma unroll
        for (int fn = 0; fn < 4; ++fn)
            acc[fm][fn] = (f32x4){0.f, 0.f, 0.f, 0.f};

    for (int k0 = 0; k0 < ENG; k0 += 64) {
        #pragma unroll
        for (int i = 0; i < 4; ++i) {
            int seg = w * 4 + i;
            gl_lds16(A + (size_t)(m0 + seg * 8 + lrow) * ENG + k0 + kcS, sA + seg * 512);
            gl_lds16(Bt + (size_t)(n0 + seg * 8 + lrow) * ENG + k0 + kcS, sB + seg * 512);
        }
        __syncthreads();
        #pragma unroll
        for (int ks = 0; ks < 2; ++ks) {
            bf16x8 af[4], bfr[4];
            int kc = ks * 4 + quad;
            #pragma unroll
            for (int f = 0; f < 4; ++f) {
                int ra = mw + f * 16 + lane15;
                int rb = nw + f * 16 + lane15;
                af[f]  = *(const bf16x8*)(sA + ra * 64 + ((kc ^ (ra & 7)) * 8));
                bfr[f] = *(const bf16x8*)(sB + rb * 64 + ((kc ^ (rb & 7)) * 8));
            }
            #pragma unroll
            for (int fm = 0; fm < 4; ++fm)
                #pragma unroll
                for (int fn = 0; fn < 4; ++fn)
                    acc[fm][fn] = __builtin_amdgcn_mfma_f32_16x16x32_bf16(
                        af[fm], bfr[fn], acc[fm][fn], 0, 0, 0);
        }
        __syncthreads();
    }
    // epilogue: C = acc + bias, p_v2[m] += sum_n v^2
    #pragma unroll
    for (int fm = 0; fm < 4; ++fm) {
        #pragma unroll
        for (int r = 0; r < 4; ++r) {
            int m = m0 + mw + fm * 16 + quad * 4 + r;
            float sv = 0.f;
            #pragma unroll
            for (int fn = 0; fn < 4; ++fn) {
                int n = n0 + nw + fn * 16 + lane15;
                float v = acc[fm][fn][r] + bias[n];
                C[(size_t)m * HID + n] = v;
                sv += v * v;
            }
            sv += __shfl_xor(sv, 1); sv += __shfl_xor(sv, 2);
            sv += __shfl_xor(sv, 4); sv += __shfl_xor(sv, 8);
            if (lane15 == 0) atomicAdd(&pv2[m], sv);
        }
    }
}

// ============================================================
// 4) keys MFMA GEMM, fused gate partials (keys never stored)
// ============================================================
__global__ __launch_bounds__(256, 1) void gemm_keys_mfma(
        const bf16* __restrict__ A,
        const bf16* __restrict__ kwT,    // [HC][HID][ENG] bf16
        const float* __restrict__ key_b, // [HC][HID]
        const float* __restrict__ hidden,// [MTOK][HID] fp32
        const float* __restrict__ w1,
        const float* __restrict__ w2,
        float* __restrict__ p_sq,        // [MTOK][HC]
        float* __restrict__ p_dot)       // [MTOK][HC]
{
    __shared__ __align__(16) bf16 sA[128 * 64];
    __shared__ __align__(16) bf16 sB[128 * 64];
    int tid = threadIdx.x;
    int L = tid & 63, w = tid >> 6;
    int m0 = blockIdx.y * 128;
    int c0 = blockIdx.x * 128;          // col in [0, HC*HID)
    int g = c0 >> 11;
    int nc0 = c0 & (HID - 1);
    const bf16* Bt = kwT + (size_t)g * HID * ENG;
    int mw = (w & 1) * 64, nw = (w >> 1) * 64;
    int lrow = L >> 3;
    int kcS = ((L & 7) ^ lrow) * 8;
    int lane15 = L & 15, quad = L >> 4;

    f32x4 acc[4][4];
    #pragma unroll
    for (int fm = 0; fm < 4; ++fm)
        #pragma unroll
        for (int fn = 0; fn < 4; ++fn)
            acc[fm][fn] = (f32x4){0.f, 0.f, 0.f, 0.f};

    for (int k0 = 0; k0 < ENG; k0 += 64) {
        #pragma unroll
        for (int i = 0; i < 4; ++i) {
            int seg = w * 4 + i;
            gl_lds16(A  + (size_t)(m0  + seg * 8 + lrow) * ENG + k0 + kcS, sA + seg * 512);
            gl_lds16(Bt + (size_t)(nc0 + seg * 8 + lrow) * ENG + k0 + kcS, sB + seg * 512);
        }
        __syncthreads();
        #pragma unroll
        for (int ks = 0; ks < 2; ++ks) {
            bf16x8 af[4], bfr[4];
            int kc = ks * 4 + quad;
            #pragma unroll
            for (int f = 0; f < 4; ++f) {
                int ra = mw + f * 16 + lane15;
                int rb = nw + f * 16 + lane15;
                af[f]  = *(const bf16x8*)(sA + ra * 64 + ((kc ^ (ra & 7)) * 8));
                bfr[f] = *(const bf16x8*)(sB + rb * 64 + ((kc ^ (rb & 7)) * 8));
            }
            #pragma unroll
            for (int fm = 0; fm < 4; ++fm)
                #pragma unroll
                for (int fn = 0; fn < 4; ++fn)
                    acc[fm][fn] = __builtin_amdgcn_mfma_f32_16x16x32_bf16(
                        af[fm], bfr[fn], acc[fm][fn], 0, 0, 0);
        }
        __syncthreads();
    }
    // epilogue: per-row partials of keys^2 and keys*hid*w1*w2
    const float* kb = key_b + (size_t)g * HID;
    const float* w1g = w1 + (size_t)g * HID;
    const float* w2g = w2 + (size_t)g * HID;
    #pragma unroll
    for (int fm = 0; fm < 4; ++fm) {
        #pragma unroll
        for (int r = 0; r < 4; ++r) {
            int m = m0 + mw + fm * 16 + quad * 4 + r;
            float psq = 0.f, pdt = 0.f;
            #pragma unroll
            for (int fn = 0; fn < 4; ++fn) {
                int nc = nc0 + nw + fn * 16 + lane15;
                float v = acc[fm][fn][r] + kb[nc];
                float hv = hidden[(size_t)m * HID + nc];
                float ww = w1g[nc] * w2g[nc];
                psq += v * v;
                pdt += v * hv * ww;
            }
            psq += __shfl_xor(psq, 1); psq += __shfl_xor(psq, 2);
            psq += __shfl_xor(psq, 4); psq += __shfl_xor(psq, 8);
            pdt += __shfl_xor(pdt, 1); pdt += __shfl_xor(pdt, 2);
            pdt += __shfl_xor(pdt, 4); pdt += __shfl_xor(pdt, 8);
            if (lane15 == 0) {
                atomicAdd(&p_sq[(size_t)m * HC + g], psq);
                atomicAdd(&p_dot[(size_t)m * HC + g], pdt);
            }
        }
    }
}

// ============================================================
// 5) mq = mean(hidden^2) per token — one wave per token
// ============================================================
__global__ __launch_bounds__(256) void mq_kernel(
        const float* __restrict__ hidden, float* __restrict__ mq)
{
    int w = threadIdx.x >> 6, L = threadIdx.x & 63;
    int t = blockIdx.x * 4 + w;
    const float4* hp = (const float4*)(hidden + (size_t)t * HID);
    float s = 0.f;
    #pragma unroll
    for (int i = 0; i < 8; ++i) {
        float4 h = hp[L + i * 64];
        s += h.x * h.x + h.y * h.y + h.z * h.z + h.w * h.w;
    }
    #pragma unroll
    for (int msk = 1; msk < 64; msk <<= 1) s += __shfl_xor(s, msk);
    if (L == 0) mq[t] = s * (1.0f / HID);
}

// ============================================================
// 6) gate finalize
// ============================================================
__global__ __launch_bounds__(256) void finalize_kernel(
        const float* __restrict__ p_sq,
        const float* __restrict__ p_dot,
        const float* __restrict__ mq,
        const float* __restrict__ pv2,
        float* __restrict__ gate,
        float* __restrict__ cc)
{
    int i = blockIdx.x * 256 + threadIdx.x;
    if (i >= MTOK * HC) return;
    int t = i >> 2;
    float mk = p_sq[i] * (1.0f / HID) + EPS_RMS;
    float mqv = mq[t] + EPS_RMS;
    float raw = p_dot[i] * rsqrtf(mk) * rsqrtf(mqv) * INV_SQRT_HID;
    float g2 = copysignf(sqrtf(fmaxf(fabsf(raw), 1e-6f)), raw);
    float gt = 1.0f / (1.0f + expf(-g2));
    gate[i] = gt;
    float msqv = pv2[t] * (1.0f / HID);
    cc[i] = gt * rsqrtf(gt * gt * msqv + EPS_SC);
}

// ============================================================
// 7) fused conv + silu + gated-value + channel sum
// ============================================================
__global__ __launch_bounds__(256) void final_kernel(
        const float* __restrict__ vraw,
        const float* __restrict__ gate,
        const float* __restrict__ cc,
        const float* __restrict__ sc_w,   // [HC][HID]
        const float* __restrict__ conv_w, // [HC*HID][4]
        float* __restrict__ out)
{
    int t = blockIdx.x;
    int l = t & (LQ - 1);
    int tid = threadIdx.x;
    float G = gate[t * 4 + 0] + gate[t * 4 + 1] + gate[t * 4 + 2] + gate[t * 4 + 3];
    float cg[4][4];
    int tki[4];
    #pragma unroll
    for (int k = 0; k < 4; ++k) {
        int lk = l + 3 * k - 9;
        bool valid = (lk >= 0);
        int tk = t + 3 * k - 9;
        tki[k] = valid ? tk : -1;
        #pragma unroll
        for (int g = 0; g < 4; ++g)
            cg[k][g] = valid ? cc[tk * 4 + g] : 0.0f;
    }
    #pragma unroll
    for (int i = 0; i < 2; ++i) {
        int h4 = tid + i * 256;
        float4 vk[4];
        #pragma unroll
        for (int k = 0; k < 4; ++k) {
            vk[k] = (tki[k] >= 0)
                  ? ((const float4*)(vraw + (size_t)tki[k] * HID))[h4]
                  : make_float4(0.f, 0.f, 0.f, 0.f);
        }
        float res[4];
        #pragma unroll
        for (int j = 0; j < 4; ++j) {
            int h = h4 * 4 + j;
            float vt = ((const float*)&vk[3])[j];
            float o = vt * G;
            #pragma unroll
            for (int g = 0; g < 4; ++g) {
                float4 w4 = ((const float4*)conv_w)[(size_t)g * HID + h];
                float y = w4.x * cg[0][g] * ((const float*)&vk[0])[j]
                        + w4.y * cg[1][g] * ((const float*)&vk[1])[j]
                        + w4.z * cg[2][g] * ((const float*)&vk[2])[j]
                        + w4.w * cg[3][g] * ((const float*)&vk[3])[j];
                y *= sc_w[(size_t)g * HID + h];
                o += y / (1.0f + expf(-y));
            }
            res[j] = o;
        }
        ((float4*)(out + (size_t)t * HID))[h4] = make_float4(res[0], res[1], res[2], res[3]);
    }
}

// ============================================================
extern "C" void kernel_launch(void* const* d_in, const int* in_sizes, int n_in,
                              void* d_out, int out_size, void* d_ws, size_t ws_size,
                              hipStream_t stream)
{
    const float* hidden     = (const float*)d_in[0];
    const int*   hash_ids   = (const int*)  d_in[1];
    const float* emb_tables = (const float*)d_in[2];
    const float* value_w    = (const float*)d_in[3];
    const float* value_b    = (const float*)d_in[4];
    const float* key_w      = (const float*)d_in[5];
    const float* key_b      = (const float*)d_in[6];
    const float* norm1_w    = (const float*)d_in[7];
    const float* norm2_w    = (const float*)d_in[8];
    const float* sc_norm_w  = (const float*)d_in[9];
    const float* conv_w     = (const float*)d_in[10];
    float* out = (float*)d_out;

    char* ws = (char*)d_ws;
    bf16*  ws_emb  = (bf16*)ws;  ws += sizeof(bf16) * (size_t)MTOK * ENG;        // 16 MB
    bf16*  ws_vwT  = (bf16*)ws;  ws += sizeof(bf16) * (size_t)HID * ENG;         // 4 MB
    bf16*  ws_kwT  = (bf16*)ws;  ws += sizeof(bf16) * (size_t)HC * HID * ENG;    // 16 MB
    float* ws_vraw = (float*)ws; ws += sizeof(float) * (size_t)MTOK * HID;       // 64 MB
    float* ws_psq  = (float*)ws; ws += sizeof(float) * (size_t)MTOK * HC;
    float* ws_pdot = (float*)ws; ws += sizeof(float) * (size_t)MTOK * HC;
    float* ws_pv2  = (float*)ws; ws += sizeof(float) * (size_t)MTOK;
    float* ws_mq   = (float*)ws; ws += sizeof(float) * (size_t)MTOK;
    float* ws_gate = (float*)ws; ws += sizeof(float) * (size_t)MTOK * HC;
    float* ws_cc   = (float*)ws; ws += sizeof(float) * (size_t)MTOK * HC;

    // zero atomic accumulators (psq, pdot, pv2 are contiguous)
    hipMemsetAsync(ws_psq, 0, sizeof(float) * ((size_t)MTOK * HC * 2 + MTOK), stream);

    transpose_kernel<<<dim3(HID / 32, ENG / 32, 5), 256, 0, stream>>>(
        value_w, key_w, ws_vwT, ws_kwT);

    gather_kernel<<<MTOK, 256, 0, stream>>>(hash_ids, emb_tables, ws_emb);

    gemm_value_mfma<<<dim3(HID / 128, MTOK / 128), 256, 0, stream>>>(
        ws_emb, ws_vwT, value_b, ws_vraw, ws_pv2);

    gemm_keys_mfma<<<dim3(HC * HID / 128, MTOK / 128), 256, 0, stream>>>(
        ws_emb, ws_kwT, key_b, hidden, norm1_w, norm2_w, ws_psq, ws_pdot);

    mq_kernel<<<MTOK / 4, 256, 0, stream>>>(hidden, ws_mq);

    finalize_kernel<<<(MTOK * HC + 255) / 256, 256, 0, stream>>>(
        ws_psq, ws_pdot, ws_mq, ws_pv2, ws_gate, ws_cc);

    final_kernel<<<MTOK, 256, 0, stream>>>(
        ws_vraw, ws_gate, ws_cc, sc_norm_w, conv_w, out);
}